// Round 10
// baseline (119.947 us; speedup 1.0000x reference)
//
#include <hip/hip_runtime.h>

constexpr int NB     = 8 * 32 * 96 * 96;   // 2359296 output elements
constexpr int NQUAD  = NB / 4;             // 589824 quads of 4 adjacent-ho outputs
constexpr int NACC   = 44;                 // 8 sums + 36 upper-tri Gram entries
constexpr int GRID_A = 1024;
constexpr int TPB    = 256;
constexpr int GRID_P = 1024;               // 4 blocks/CU guaranteed co-resident (spin-safe)

// ---------------- Kernel A: sums + Gram partial reduction (quad/float4x2) ----------------
__global__ __launch_bounds__(TPB, 4)
void reduce_kernel(const float* __restrict__ x, float* __restrict__ partials,
                   unsigned int* __restrict__ ctr, unsigned int* __restrict__ flag) {
  if (blockIdx.x == 0 && threadIdx.x == 0) { *ctr = 0u; *flag = 0u; }  // per-launch reset

  float acc[NACC];
#pragma unroll
  for (int i = 0; i < NACC; ++i) acc[i] = 0.0f;

  int tid = blockIdx.x * TPB + threadIdx.x;
  const int stride = GRID_A * TPB;
  for (int q = tid; q < NQUAD; q += stride) {
    int hq = q % 24;
    int t1 = q / 24;
    int wo = t1 % 96;
    int t2 = t1 / 96;
    int so = t2 % 32;
    int b  = t2 / 32;
    const float* base = x + (((b * 64 + 2 * so) * 192 + 2 * wo) * 192 + 8 * hq);
    float4 a0 = *(const float4*)(base);
    float4 b0 = *(const float4*)(base + 4);
    float4 a1 = *(const float4*)(base + 192);
    float4 b1 = *(const float4*)(base + 196);
    float4 a2 = *(const float4*)(base + 192 * 192);
    float4 b2 = *(const float4*)(base + 192 * 192 + 4);
    float4 a3 = *(const float4*)(base + 192 * 192 + 192);
    float4 b3 = *(const float4*)(base + 192 * 192 + 196);
    float P[4][8] = {
      {a0.x, a0.y, a1.x, a1.y, a2.x, a2.y, a3.x, a3.y},
      {a0.z, a0.w, a1.z, a1.w, a2.z, a2.w, a3.z, a3.w},
      {b0.x, b0.y, b1.x, b1.y, b2.x, b2.y, b3.x, b3.y},
      {b0.z, b0.w, b1.z, b1.w, b2.z, b2.w, b3.z, b3.w}};
#pragma unroll
    for (int a = 0; a < 8; ++a)
      acc[a] += (P[0][a] + P[1][a]) + (P[2][a] + P[3][a]);
    int k = 8;
#pragma unroll
    for (int a = 0; a < 8; ++a)
#pragma unroll
      for (int c = a; c < 8; ++c) {
        float t = P[0][a] * P[0][c];
        t += P[1][a] * P[1][c];
        t += P[2][a] * P[2][c];
        t += P[3][a] * P[3][c];
        acc[k++] += t;
      }
  }

  // wave shuffle reduce (64 lanes)
#pragma unroll
  for (int i = 0; i < NACC; ++i) {
    float v = acc[i];
    for (int off = 32; off >= 1; off >>= 1) v += __shfl_down(v, off, 64);
    acc[i] = v;
  }
  __shared__ float lds[4][NACC];
  int lane = threadIdx.x & 63;
  int wv   = threadIdx.x >> 6;
  if (lane == 0) {
#pragma unroll
    for (int i = 0; i < NACC; ++i) lds[wv][i] = acc[i];
  }
  __syncthreads();
  if (threadIdx.x < NACC) {
    float s = lds[0][threadIdx.x] + lds[1][threadIdx.x] +
              lds[2][threadIdx.x] + lds[3][threadIdx.x];
    partials[threadIdx.x * GRID_A + blockIdx.x] = s;  // transposed: contiguous rows
  }
}

// ---- readlane helper: compile-time lane gather (no LDS round-trip) ----
__device__ __forceinline__ float rdlane(float x, int lane) {
  return __int_as_float(__builtin_amdgcn_readlane(__float_as_int(x), lane));
}

// ---- Jacobi rotation angles: fast-math (v_rcp/v_sqrt/v_rsq), ~12 VALU ----
template <int P, int Q>
__device__ __forceinline__ void jrot(const float (&r)[8], float& ct, float& st) {
  float app = rdlane(r[P], P);
  float aqq = rdlane(r[Q], Q);
  float apq = rdlane(r[Q], P);
  float theta = (aqq - app) * 0.5f * __builtin_amdgcn_rcpf(apq);
  float root  = __builtin_amdgcn_sqrtf(theta * theta + 1.0f);
  float tmag  = __builtin_amdgcn_rcpf(fabsf(theta) + root);
  float tt    = copysignf(tmag, theta);
  float c     = __builtin_amdgcn_rsqf(tt * tt + 1.0f);
  float s     = tt * c;
  bool zero   = (apq == 0.0f);
  ct = zero ? 1.0f : c;
  st = zero ? 0.0f : s;
}

template <int P, int Q>
__device__ __forceinline__ void jcol(float (&r)[8], float (&v)[8], float c, float s) {
  float rp = r[P], rq = r[Q];
  r[P] = c * rp - s * rq;
  r[Q] = s * rp + c * rq;
  float vp = v[P], vq = v[Q];
  v[P] = c * vp - s * vq;
  v[Q] = s * vp + c * vq;
}

template <int P0,int Q0,int P1,int Q1,int P2,int Q2,int P3,int Q3>
__device__ __forceinline__ void jacobi_round(float (&r)[8], float (&v)[8], int i) {
  float c0,s0,c1,s1,c2,s2,c3,s3;
  jrot<P0,Q0>(r, c0, s0);
  jrot<P1,Q1>(r, c1, s1);
  jrot<P2,Q2>(r, c2, s2);
  jrot<P3,Q3>(r, c3, s3);
  jcol<P0,Q0>(r, v, c0, s0);
  jcol<P1,Q1>(r, v, c1, s1);
  jcol<P2,Q2>(r, v, c2, s2);
  jcol<P3,Q3>(r, v, c3, s3);
  float alpha = 1.0f, beta = 0.0f;
  int plane = i;
  if (i == P0) { alpha = c0; beta = -s0; plane = Q0; }
  if (i == Q0) { alpha = c0; beta =  s0; plane = P0; }
  if (i == P1) { alpha = c1; beta = -s1; plane = Q1; }
  if (i == Q1) { alpha = c1; beta =  s1; plane = P1; }
  if (i == P2) { alpha = c2; beta = -s2; plane = Q2; }
  if (i == Q2) { alpha = c2; beta =  s2; plane = P2; }
  if (i == P3) { alpha = c3; beta = -s3; plane = Q3; }
  if (i == Q3) { alpha = c3; beta =  s3; plane = P3; }
  float prow[8];
#pragma unroll
  for (int j = 0; j < 8; ++j) prow[j] = __shfl(r[j], plane, 64);
#pragma unroll
  for (int j = 0; j < 8; ++j) r[j] = alpha * r[j] + beta * prow[j];
}

// ---- Kernel C: first 44 blocks mid-reduce, last solves + flags; all project ----
__global__ __launch_bounds__(TPB, 4)
void project_solve_kernel(const float* __restrict__ x,
                          const float* __restrict__ partials,
                          double* __restrict__ sums_d,
                          unsigned int* __restrict__ ctr,
                          unsigned int* __restrict__ flag,
                          float* __restrict__ res,
                          float* __restrict__ out,
                          float* __restrict__ out_tail) {
  int t = threadIdx.x;

  if (blockIdx.x < NACC) {
    // mid-reduce this acc's 1024-float row (coalesced float4, f64 accumulate)
    const float* row = partials + blockIdx.x * GRID_A;
    float4 u = ((const float4*)row)[t];
    double s = (double)u.x + (double)u.y + (double)u.z + (double)u.w;
    for (int off = 32; off >= 1; off >>= 1) s += __shfl_down(s, off, 64);
    __shared__ double ldsd[4];
    __shared__ bool is_last;
    if ((t & 63) == 0) ldsd[t >> 6] = s;
    __syncthreads();
    if (t == 0) {
      sums_d[blockIdx.x] = ldsd[0] + ldsd[1] + ldsd[2] + ldsd[3];
      __threadfence();                                // release sums_d
      unsigned int old = atomicAdd(ctr, 1u);
      is_last = (old == (unsigned int)(NACC - 1));
    }
    __syncthreads();
    if (is_last) {
      __threadfence();                                // acquire all sums_d
      __shared__ double sums[NACC];
      if (t < NACC) sums[t] = sums_d[t];
      __syncthreads();
      if (t < 64) {
        const int i = t & 7;
        const double invN = 1.0 / (double)NB;
        double mean[8];
#pragma unroll
        for (int j = 0; j < 8; ++j) mean[j] = sums[j] * invN;
        double mean_i = mean[0];
#pragma unroll
        for (int k = 1; k < 8; ++k) if (i == k) mean_i = mean[k];
        double rowd[8];
#pragma unroll
        for (int j = 0; j < 8; ++j) {
          int p = i < j ? i : j;
          int q = i < j ? j : i;
          int idx = 8 + p * 8 - (p * (p - 1)) / 2 + (q - p);
          rowd[j] = sums[idx] - (double)NB * mean_i * mean[j];
        }
        double tr = 0.0;
#pragma unroll
        for (int k = 0; k < 8; ++k) tr += __shfl(rowd[k], k, 64);
        double shift = tr * 0.125;

        float r[8], v[8];
#pragma unroll
        for (int j = 0; j < 8; ++j) {
          double d = rowd[j] - (j == i ? shift : 0.0);
          r[j] = (float)(d * (1.0 / 1536.0));
          v[j] = (j == i) ? 1.0f : 0.0f;
        }
#pragma unroll 1
        for (int sweep = 0; sweep < 6; ++sweep) {
          jacobi_round<7,0, 1,6, 2,5, 3,4>(r, v, i);
          jacobi_round<7,1, 2,0, 3,6, 4,5>(r, v, i);
          jacobi_round<7,2, 3,1, 4,0, 5,6>(r, v, i);
          jacobi_round<7,3, 4,2, 5,1, 6,0>(r, v, i);
          jacobi_round<7,4, 5,3, 6,2, 0,1>(r, v, i);
          jacobi_round<7,5, 6,4, 0,3, 1,2>(r, v, i);
          jacobi_round<7,6, 0,5, 1,4, 2,3>(r, v, i);
        }
        float diag[8];
#pragma unroll
        for (int k = 0; k < 8; ++k) diag[k] = rdlane(r[k], k);
        int best = 0; float bd = diag[0];
#pragma unroll
        for (int k = 1; k < 8; ++k) if (diag[k] > bd) { bd = diag[k]; best = k; }
        float vi = v[0];
#pragma unroll
        for (int k = 1; k < 8; ++k) if (best == k) vi = v[k];
        float vec[8];
#pragma unroll
        for (int k = 0; k < 8; ++k) vec[k] = rdlane(vi, k);
        float nrm2 = 0.0f;
#pragma unroll
        for (int k = 0; k < 8; ++k) nrm2 += vec[k] * vec[k];
        float inv = 1.0f / sqrtf(nrm2);
#pragma unroll
        for (int k = 0; k < 8; ++k) vec[k] *= inv;
        // sign convention (measured vs LAPACK round 1/2): largest-|component| NEGATIVE
        int m = 0; float am = fabsf(vec[0]);
#pragma unroll
        for (int k = 1; k < 8; ++k) { float aa = fabsf(vec[k]); if (aa > am) { am = aa; m = k; } }
        float vm = vec[0];
#pragma unroll
        for (int k = 1; k < 8; ++k) if (m == k) vm = vec[k];
        if (vm > 0.0f) {
#pragma unroll
          for (int k = 0; k < 8; ++k) vec[k] = -vec[k];
        }
        double c0d = 0.0;
#pragma unroll
        for (int k = 0; k < 8; ++k) c0d += mean[k] * (double)vec[k];
        float mi = (float)mean[0];
#pragma unroll
        for (int k = 1; k < 8; ++k) if (i == k) mi = (float)mean[k];
        float vl = vec[0];
#pragma unroll
        for (int k = 1; k < 8; ++k) if (i == k) vl = vec[k];
        if (t < 8) {
          res[t]          = vl;   // projection weights
          out_tail[t]     = mi;   // mean
          out_tail[8 + t] = vl;   // pca_components
        }
        if (t == 0) res[8] = (float)c0d;
      }
      __syncthreads();
      if (t == 0) {
        __threadfence();          // drain res stores to L2
        __hip_atomic_store(flag, 1u, __ATOMIC_RELEASE, __HIP_MEMORY_SCOPE_AGENT);
      }
    }
  }

  // all blocks: wait for res (setters never wait -> no deadlock; all blocks co-resident)
  __shared__ float s_res[9];
  if (t == 0) {
    while (__hip_atomic_load(flag, __ATOMIC_ACQUIRE, __HIP_MEMORY_SCOPE_AGENT) == 0u)
      __builtin_amdgcn_s_sleep(2);
  }
  __syncthreads();
  if (t < 9)
    s_res[t] = __hip_atomic_load(&res[t], __ATOMIC_RELAXED, __HIP_MEMORY_SCOPE_AGENT);
  __syncthreads();

  float w0 = s_res[0], w1 = s_res[1], w2 = s_res[2], w3 = s_res[3];
  float w4 = s_res[4], w5 = s_res[5], w6 = s_res[6], w7 = s_res[7];
  float c0 = s_res[8];
  float4* out4 = (float4*)out;
  const int stride = GRID_P * TPB;
  for (int q = blockIdx.x * TPB + t; q < NQUAD; q += stride) {
    int hq = q % 24;
    int t1 = q / 24;
    int wo = t1 % 96;
    int t2 = t1 / 96;
    int so = t2 % 32;
    int b  = t2 / 32;
    const float* base = x + (((b * 64 + 2 * so) * 192 + 2 * wo) * 192 + 8 * hq);
    float4 a0 = *(const float4*)(base);
    float4 b0 = *(const float4*)(base + 4);
    float4 a1 = *(const float4*)(base + 192);
    float4 b1 = *(const float4*)(base + 196);
    float4 a2 = *(const float4*)(base + 192 * 192);
    float4 b2 = *(const float4*)(base + 192 * 192 + 4);
    float4 a3 = *(const float4*)(base + 192 * 192 + 192);
    float4 b3 = *(const float4*)(base + 192 * 192 + 196);
    float o0 = a0.x * w0 + a0.y * w1 + a1.x * w2 + a1.y * w3
             + a2.x * w4 + a2.y * w5 + a3.x * w6 + a3.y * w7 - c0;
    float o1 = a0.z * w0 + a0.w * w1 + a1.z * w2 + a1.w * w3
             + a2.z * w4 + a2.w * w5 + a3.z * w6 + a3.w * w7 - c0;
    float o2 = b0.x * w0 + b0.y * w1 + b1.x * w2 + b1.y * w3
             + b2.x * w4 + b2.y * w5 + b3.x * w6 + b3.y * w7 - c0;
    float o3 = b0.z * w0 + b0.w * w1 + b1.z * w2 + b1.w * w3
             + b2.z * w4 + b2.w * w5 + b3.z * w6 + b3.w * w7 - c0;
    out4[q] = make_float4(o0, o1, o2, o3);
  }
}

extern "C" void kernel_launch(void* const* d_in, const int* in_sizes, int n_in,
                              void* d_out, int out_size, void* d_ws, size_t ws_size,
                              hipStream_t stream) {
  (void)in_sizes; (void)n_in; (void)out_size; (void)ws_size;
  const float* x = (const float*)d_in[0];
  float* out = (float*)d_out;
  float* partials   = (float*)d_ws;                          // 44*1024 f32 = 176 KB
  double* sums_d    = (double*)(partials + NACC * GRID_A);   // 44 f64 (8B-aligned)
  float* res        = (float*)(sums_d + NACC);               // 9 f32 (pad to 16)
  unsigned int* ctr = (unsigned int*)(res + 16);             // u32
  unsigned int* flg = ctr + 1;                               // u32

  reduce_kernel<<<GRID_A, TPB, 0, stream>>>(x, partials, ctr, flg);
  project_solve_kernel<<<GRID_P, TPB, 0, stream>>>(x, partials, sums_d, ctr, flg,
                                                   res, out, out + NB);
}

// Round 11
// 73.998 us; speedup vs baseline: 1.6209x; 1.6209x over previous
//
#include <hip/hip_runtime.h>

constexpr int NB     = 8 * 32 * 96 * 96;   // 2359296 output elements
constexpr int NPAIR  = NB / 2;             // 1179648 adjacent-ho pairs
constexpr int NACC   = 44;                 // 8 sums + 36 upper-tri Gram entries
constexpr int GRID_A = 1024;
constexpr int TPB    = 256;
constexpr int GRID_P = 2048;               // 8 blocks/CU -> 32 waves/CU streaming

// ---------------- Kernel A: sums + Gram partial reduction (pair/float4) ----------------
__global__ __launch_bounds__(TPB, 4)
void reduce_kernel(const float* __restrict__ x, float* __restrict__ partials,
                   unsigned int* __restrict__ ctr, unsigned int* __restrict__ flag) {
  if (blockIdx.x == 0 && threadIdx.x == 0) { *ctr = 0u; *flag = 0u; }  // per-launch reset

  float acc[NACC];
#pragma unroll
  for (int i = 0; i < NACC; ++i) acc[i] = 0.0f;

  int tid = blockIdx.x * TPB + threadIdx.x;
  const int stride = GRID_A * TPB;
  for (int p = tid; p < NPAIR; p += stride) {
    int hp = p % 48;
    int t1 = p / 48;
    int wo = t1 % 96;
    int t2 = t1 / 96;
    int so = t2 % 32;
    int b  = t2 / 32;
    const float* base = x + (((b * 64 + 2 * so) * 192 + 2 * wo) * 192 + 4 * hp);
    float4 r0 = *(const float4*)(base);
    float4 r1 = *(const float4*)(base + 192);
    float4 r2 = *(const float4*)(base + 192 * 192);
    float4 r3 = *(const float4*)(base + 192 * 192 + 192);
    float v0[8] = {r0.x, r0.y, r1.x, r1.y, r2.x, r2.y, r3.x, r3.y};
    float v1[8] = {r0.z, r0.w, r1.z, r1.w, r2.z, r2.w, r3.z, r3.w};
#pragma unroll
    for (int a = 0; a < 8; ++a) acc[a] += v0[a] + v1[a];
    int k = 8;
#pragma unroll
    for (int a = 0; a < 8; ++a)
#pragma unroll
      for (int q = a; q < 8; ++q) acc[k++] += v0[a] * v0[q] + v1[a] * v1[q];
  }

  // wave shuffle reduce (64 lanes)
#pragma unroll
  for (int i = 0; i < NACC; ++i) {
    float v = acc[i];
    for (int off = 32; off >= 1; off >>= 1) v += __shfl_down(v, off, 64);
    acc[i] = v;
  }
  __shared__ float lds[4][NACC];
  int lane = threadIdx.x & 63;
  int wv   = threadIdx.x >> 6;
  if (lane == 0) {
#pragma unroll
    for (int i = 0; i < NACC; ++i) lds[wv][i] = acc[i];
  }
  __syncthreads();
  if (threadIdx.x < NACC) {
    float s = lds[0][threadIdx.x] + lds[1][threadIdx.x] +
              lds[2][threadIdx.x] + lds[3][threadIdx.x];
    partials[threadIdx.x * GRID_A + blockIdx.x] = s;  // transposed: contiguous rows
  }
}

// ---- readlane helper: compile-time lane gather (no LDS round-trip) ----
__device__ __forceinline__ float rdlane(float x, int lane) {
  return __int_as_float(__builtin_amdgcn_readlane(__float_as_int(x), lane));
}

// ---- Jacobi rotation angles: fast-math (v_rcp/v_sqrt/v_rsq), ~12 VALU ----
template <int P, int Q>
__device__ __forceinline__ void jrot(const float (&r)[8], float& ct, float& st) {
  float app = rdlane(r[P], P);
  float aqq = rdlane(r[Q], Q);
  float apq = rdlane(r[Q], P);
  float theta = (aqq - app) * 0.5f * __builtin_amdgcn_rcpf(apq);
  float root  = __builtin_amdgcn_sqrtf(theta * theta + 1.0f);
  float tmag  = __builtin_amdgcn_rcpf(fabsf(theta) + root);
  float tt    = copysignf(tmag, theta);
  float c     = __builtin_amdgcn_rsqf(tt * tt + 1.0f);
  float s     = tt * c;
  bool zero   = (apq == 0.0f);
  ct = zero ? 1.0f : c;
  st = zero ? 0.0f : s;
}

template <int P, int Q>
__device__ __forceinline__ void jcol(float (&r)[8], float (&v)[8], float c, float s) {
  float rp = r[P], rq = r[Q];
  r[P] = c * rp - s * rq;
  r[Q] = s * rp + c * rq;
  float vp = v[P], vq = v[Q];
  v[P] = c * vp - s * vq;
  v[Q] = s * vp + c * vq;
}

template <int P0,int Q0,int P1,int Q1,int P2,int Q2,int P3,int Q3>
__device__ __forceinline__ void jacobi_round(float (&r)[8], float (&v)[8], int i) {
  float c0,s0,c1,s1,c2,s2,c3,s3;
  jrot<P0,Q0>(r, c0, s0);
  jrot<P1,Q1>(r, c1, s1);
  jrot<P2,Q2>(r, c2, s2);
  jrot<P3,Q3>(r, c3, s3);
  jcol<P0,Q0>(r, v, c0, s0);
  jcol<P1,Q1>(r, v, c1, s1);
  jcol<P2,Q2>(r, v, c2, s2);
  jcol<P3,Q3>(r, v, c3, s3);
  float alpha = 1.0f, beta = 0.0f;
  int plane = i;
  if (i == P0) { alpha = c0; beta = -s0; plane = Q0; }
  if (i == Q0) { alpha = c0; beta =  s0; plane = P0; }
  if (i == P1) { alpha = c1; beta = -s1; plane = Q1; }
  if (i == Q1) { alpha = c1; beta =  s1; plane = P1; }
  if (i == P2) { alpha = c2; beta = -s2; plane = Q2; }
  if (i == Q2) { alpha = c2; beta =  s2; plane = P2; }
  if (i == P3) { alpha = c3; beta = -s3; plane = Q3; }
  if (i == Q3) { alpha = c3; beta =  s3; plane = P3; }
  float prow[8];
#pragma unroll
  for (int j = 0; j < 8; ++j) prow[j] = __shfl(r[j], plane, 64);
#pragma unroll
  for (int j = 0; j < 8; ++j) r[j] = alpha * r[j] + beta * prow[j];
}

// ---- Kernel C: blocks 0-43 mid-reduce (last solves + release-flag); all project ----
__global__ __launch_bounds__(TPB, 8)
void project_solve_kernel(const float* __restrict__ x,
                          const float* __restrict__ partials,
                          double* __restrict__ sums_d,
                          unsigned int* __restrict__ ctr,
                          unsigned int* __restrict__ flag,
                          float* __restrict__ res,
                          float* __restrict__ out,
                          float* __restrict__ out_tail) {
  int t = threadIdx.x;

  if (blockIdx.x < NACC) {
    // mid-reduce this acc's 1024-float row (coalesced float4, f64 accumulate)
    const float* row = partials + blockIdx.x * GRID_A;
    float4 u = ((const float4*)row)[t];
    double s = (double)u.x + (double)u.y + (double)u.z + (double)u.w;
    for (int off = 32; off >= 1; off >>= 1) s += __shfl_down(s, off, 64);
    __shared__ double ldsd[4];
    __shared__ bool is_last;
    if ((t & 63) == 0) ldsd[t >> 6] = s;
    __syncthreads();
    if (t == 0) {
      sums_d[blockIdx.x] = ldsd[0] + ldsd[1] + ldsd[2] + ldsd[3];
      __threadfence();                                // release sums_d to MALL
      unsigned int old = atomicAdd(ctr, 1u);
      is_last = (old == (unsigned int)(NACC - 1));
    }
    __syncthreads();
    if (is_last) {
      __threadfence();                                // acquire all sums_d
      __shared__ double sums[NACC];
      if (t < NACC) sums[t] = sums_d[t];
      __syncthreads();
      if (t < 64) {
        const int i = t & 7;
        const double invN = 1.0 / (double)NB;
        double mean[8];
#pragma unroll
        for (int j = 0; j < 8; ++j) mean[j] = sums[j] * invN;
        double mean_i = mean[0];
#pragma unroll
        for (int k = 1; k < 8; ++k) if (i == k) mean_i = mean[k];
        double rowd[8];
#pragma unroll
        for (int j = 0; j < 8; ++j) {
          int p = i < j ? i : j;
          int q = i < j ? j : i;
          int idx = 8 + p * 8 - (p * (p - 1)) / 2 + (q - p);
          rowd[j] = sums[idx] - (double)NB * mean_i * mean[j];
        }
        double tr = 0.0;
#pragma unroll
        for (int k = 0; k < 8; ++k) tr += __shfl(rowd[k], k, 64);
        double shift = tr * 0.125;

        float r[8], v[8];
#pragma unroll
        for (int j = 0; j < 8; ++j) {
          double d = rowd[j] - (j == i ? shift : 0.0);
          r[j] = (float)(d * (1.0 / 1536.0));
          v[j] = (j == i) ? 1.0f : 0.0f;
        }
#pragma unroll 1
        for (int sweep = 0; sweep < 6; ++sweep) {
          jacobi_round<7,0, 1,6, 2,5, 3,4>(r, v, i);
          jacobi_round<7,1, 2,0, 3,6, 4,5>(r, v, i);
          jacobi_round<7,2, 3,1, 4,0, 5,6>(r, v, i);
          jacobi_round<7,3, 4,2, 5,1, 6,0>(r, v, i);
          jacobi_round<7,4, 5,3, 6,2, 0,1>(r, v, i);
          jacobi_round<7,5, 6,4, 0,3, 1,2>(r, v, i);
          jacobi_round<7,6, 0,5, 1,4, 2,3>(r, v, i);
        }
        float diag[8];
#pragma unroll
        for (int k = 0; k < 8; ++k) diag[k] = rdlane(r[k], k);
        int best = 0; float bd = diag[0];
#pragma unroll
        for (int k = 1; k < 8; ++k) if (diag[k] > bd) { bd = diag[k]; best = k; }
        float vi = v[0];
#pragma unroll
        for (int k = 1; k < 8; ++k) if (best == k) vi = v[k];
        float vec[8];
#pragma unroll
        for (int k = 0; k < 8; ++k) vec[k] = rdlane(vi, k);
        float nrm2 = 0.0f;
#pragma unroll
        for (int k = 0; k < 8; ++k) nrm2 += vec[k] * vec[k];
        float inv = 1.0f / sqrtf(nrm2);
#pragma unroll
        for (int k = 0; k < 8; ++k) vec[k] *= inv;
        // sign convention (measured vs LAPACK round 1/2): largest-|component| NEGATIVE
        int m = 0; float am = fabsf(vec[0]);
#pragma unroll
        for (int k = 1; k < 8; ++k) { float aa = fabsf(vec[k]); if (aa > am) { am = aa; m = k; } }
        float vm = vec[0];
#pragma unroll
        for (int k = 1; k < 8; ++k) if (m == k) vm = vec[k];
        if (vm > 0.0f) {
#pragma unroll
          for (int k = 0; k < 8; ++k) vec[k] = -vec[k];
        }
        double c0d = 0.0;
#pragma unroll
        for (int k = 0; k < 8; ++k) c0d += mean[k] * (double)vec[k];
        float mi = (float)mean[0];
#pragma unroll
        for (int k = 1; k < 8; ++k) if (i == k) mi = (float)mean[k];
        float vl = vec[0];
#pragma unroll
        for (int k = 1; k < 8; ++k) if (i == k) vl = vec[k];
        if (t < 8) {
          res[t]          = vl;   // projection weights
          out_tail[t]     = mi;   // mean
          out_tail[8 + t] = vl;   // pca_components
        }
        if (t == 0) res[8] = (float)c0d;
      }
      __syncthreads();
      if (t == 0) {
        __threadfence();          // writeback res to MALL
        __hip_atomic_store(flag, 1u, __ATOMIC_RELEASE, __HIP_MEMORY_SCOPE_AGENT);
      }
    }
  }

  // all blocks: RELAXED spin (sc1 bypass, no L2 invalidate); setters never wait
  __shared__ float s_res[9];
  if (t == 0) {
    while (__hip_atomic_load(flag, __ATOMIC_RELAXED, __HIP_MEMORY_SCOPE_AGENT) == 0u)
      __builtin_amdgcn_s_sleep(8);
  }
  __syncthreads();
  if (t < 9)
    s_res[t] = __hip_atomic_load(&res[t], __ATOMIC_RELAXED, __HIP_MEMORY_SCOPE_AGENT);
  __syncthreads();

  // pair projection (grid-stride, float4 loads -> 2 outputs), r8-proven body
  float w0 = s_res[0], w1 = s_res[1], w2 = s_res[2], w3 = s_res[3];
  float w4 = s_res[4], w5 = s_res[5], w6 = s_res[6], w7 = s_res[7];
  float c0 = s_res[8];
  float2* out2 = (float2*)out;
  const int stride = GRID_P * TPB;
  for (int p = blockIdx.x * TPB + t; p < NPAIR; p += stride) {
    int hp = p % 48;
    int t1 = p / 48;
    int wo = t1 % 96;
    int t2 = t1 / 96;
    int so = t2 % 32;
    int b  = t2 / 32;
    const float* base = x + (((b * 64 + 2 * so) * 192 + 2 * wo) * 192 + 4 * hp);
    float4 r0 = *(const float4*)(base);
    float4 r1 = *(const float4*)(base + 192);
    float4 r2 = *(const float4*)(base + 192 * 192);
    float4 r3 = *(const float4*)(base + 192 * 192 + 192);
    float o0 = r0.x * w0 + r0.y * w1 + r1.x * w2 + r1.y * w3
             + r2.x * w4 + r2.y * w5 + r3.x * w6 + r3.y * w7 - c0;
    float o1 = r0.z * w0 + r0.w * w1 + r1.z * w2 + r1.w * w3
             + r2.z * w4 + r2.w * w5 + r3.z * w6 + r3.w * w7 - c0;
    out2[p] = make_float2(o0, o1);
  }
}

extern "C" void kernel_launch(void* const* d_in, const int* in_sizes, int n_in,
                              void* d_out, int out_size, void* d_ws, size_t ws_size,
                              hipStream_t stream) {
  (void)in_sizes; (void)n_in; (void)out_size; (void)ws_size;
  const float* x = (const float*)d_in[0];
  float* out = (float*)d_out;
  float* partials   = (float*)d_ws;                          // 44*1024 f32 = 176 KB
  double* sums_d    = (double*)(partials + NACC * GRID_A);   // 44 f64 (8B-aligned)
  float* res        = (float*)(sums_d + NACC);               // 9 f32 (pad to 16)
  unsigned int* ctr = (unsigned int*)(res + 16);             // u32
  unsigned int* flg = ctr + 1;                               // u32

  reduce_kernel<<<GRID_A, TPB, 0, stream>>>(x, partials, ctr, flg);
  project_solve_kernel<<<GRID_P, TPB, 0, stream>>>(x, partials, sums_d, ctr, flg,
                                                   res, out, out + NB);
}

// Round 12
// 53.539 us; speedup vs baseline: 2.2403x; 1.3821x over previous
//
#include <hip/hip_runtime.h>

constexpr int NB     = 8 * 32 * 96 * 96;   // 2359296 output elements
constexpr int NQUAD  = NB / 4;             // 589824 quads of 4 adjacent-ho outputs
constexpr int NACC   = 44;                 // 8 sums + 36 upper-tri Gram entries
constexpr int GRID_A = 768;                // 768*256*3 == NQUAD exactly (balanced)
constexpr int TPB    = 256;
constexpr int GRID_P = 768;                // balanced; 3 blocks/CU; 0.75 solve-waves/SIMD

// ---------------- Kernel A: sums + Gram partial reduction (quad/float4x8) ----------------
__global__ __launch_bounds__(TPB, 4)
void reduce_kernel(const float* __restrict__ x, float* __restrict__ partials) {
  float acc[NACC];
#pragma unroll
  for (int i = 0; i < NACC; ++i) acc[i] = 0.0f;

  int tid = blockIdx.x * TPB + threadIdx.x;
  const int stride = GRID_A * TPB;
  for (int q = tid; q < NQUAD; q += stride) {   // exactly 3 iterations/thread
    int hq = q % 24;
    int t1 = q / 24;
    int wo = t1 % 96;
    int t2 = t1 / 96;
    int so = t2 % 32;
    int b  = t2 / 32;
    const float* base = x + (((b * 64 + 2 * so) * 192 + 2 * wo) * 192 + 8 * hq);
    float4 a0 = *(const float4*)(base);
    float4 b0 = *(const float4*)(base + 4);
    float4 a1 = *(const float4*)(base + 192);
    float4 b1 = *(const float4*)(base + 196);
    float4 a2 = *(const float4*)(base + 192 * 192);
    float4 b2 = *(const float4*)(base + 192 * 192 + 4);
    float4 a3 = *(const float4*)(base + 192 * 192 + 192);
    float4 b3 = *(const float4*)(base + 192 * 192 + 196);
    float P[4][8] = {
      {a0.x, a0.y, a1.x, a1.y, a2.x, a2.y, a3.x, a3.y},
      {a0.z, a0.w, a1.z, a1.w, a2.z, a2.w, a3.z, a3.w},
      {b0.x, b0.y, b1.x, b1.y, b2.x, b2.y, b3.x, b3.y},
      {b0.z, b0.w, b1.z, b1.w, b2.z, b2.w, b3.z, b3.w}};
#pragma unroll
    for (int a = 0; a < 8; ++a)
      acc[a] += (P[0][a] + P[1][a]) + (P[2][a] + P[3][a]);
    int k = 8;
#pragma unroll
    for (int a = 0; a < 8; ++a)
#pragma unroll
      for (int c = a; c < 8; ++c) {
        float t = P[0][a] * P[0][c];
        t += P[1][a] * P[1][c];
        t += P[2][a] * P[2][c];
        t += P[3][a] * P[3][c];
        acc[k++] += t;
      }
  }

  // wave shuffle reduce (64 lanes)
#pragma unroll
  for (int i = 0; i < NACC; ++i) {
    float v = acc[i];
    for (int off = 32; off >= 1; off >>= 1) v += __shfl_down(v, off, 64);
    acc[i] = v;
  }
  __shared__ float lds[4][NACC];
  int lane = threadIdx.x & 63;
  int wv   = threadIdx.x >> 6;
  if (lane == 0) {
#pragma unroll
    for (int i = 0; i < NACC; ++i) lds[wv][i] = acc[i];
  }
  __syncthreads();
  if (threadIdx.x < NACC) {
    float s = lds[0][threadIdx.x] + lds[1][threadIdx.x] +
              lds[2][threadIdx.x] + lds[3][threadIdx.x];
    partials[threadIdx.x * GRID_A + blockIdx.x] = s;  // transposed: contiguous rows
  }
}

// ------- Kernel A2: per-acc parallel reduce, 44 blocks -> sums_d (f64) -------
__global__ __launch_bounds__(TPB)
void mid_reduce_kernel(const float* __restrict__ partials, double* __restrict__ sums_d) {
  int a = blockIdx.x;
  int t = threadIdx.x;
  const float* row = partials + a * GRID_A;
  double s = (double)row[t] + (double)row[t + 256] + (double)row[t + 512];
  for (int off = 32; off >= 1; off >>= 1) s += __shfl_down(s, off, 64);
  __shared__ double lds[4];
  if ((t & 63) == 0) lds[t >> 6] = s;
  __syncthreads();
  if (t == 0) sums_d[a] = lds[0] + lds[1] + lds[2] + lds[3];
}

// ---- readlane helper: compile-time lane gather (no LDS round-trip) ----
__device__ __forceinline__ float rdlane(float x, int lane) {
  return __int_as_float(__builtin_amdgcn_readlane(__float_as_int(x), lane));
}

// ---- Jacobi rotation angles: fast-math (v_rcp/v_sqrt/v_rsq), ~12 VALU ----
template <int P, int Q>
__device__ __forceinline__ void jrot(const float (&r)[8], float& ct, float& st) {
  float app = rdlane(r[P], P);
  float aqq = rdlane(r[Q], Q);
  float apq = rdlane(r[Q], P);
  float theta = (aqq - app) * 0.5f * __builtin_amdgcn_rcpf(apq);
  float root  = __builtin_amdgcn_sqrtf(theta * theta + 1.0f);
  float tmag  = __builtin_amdgcn_rcpf(fabsf(theta) + root);
  float tt    = copysignf(tmag, theta);
  float c     = __builtin_amdgcn_rsqf(tt * tt + 1.0f);
  float s     = tt * c;
  bool zero   = (apq == 0.0f);
  ct = zero ? 1.0f : c;
  st = zero ? 0.0f : s;
}

template <int P, int Q>
__device__ __forceinline__ void jcol(float (&r)[8], float (&v)[8], float c, float s) {
  float rp = r[P], rq = r[Q];
  r[P] = c * rp - s * rq;
  r[Q] = s * rp + c * rq;
  float vp = v[P], vq = v[Q];
  v[P] = c * vp - s * vq;
  v[Q] = s * vp + c * vq;
}

template <int P0,int Q0,int P1,int Q1,int P2,int Q2,int P3,int Q3>
__device__ __forceinline__ void jacobi_round(float (&r)[8], float (&v)[8], int i) {
  float c0,s0,c1,s1,c2,s2,c3,s3;
  jrot<P0,Q0>(r, c0, s0);
  jrot<P1,Q1>(r, c1, s1);
  jrot<P2,Q2>(r, c2, s2);
  jrot<P3,Q3>(r, c3, s3);
  jcol<P0,Q0>(r, v, c0, s0);
  jcol<P1,Q1>(r, v, c1, s1);
  jcol<P2,Q2>(r, v, c2, s2);
  jcol<P3,Q3>(r, v, c3, s3);
  float alpha = 1.0f, beta = 0.0f;
  int plane = i;
  if (i == P0) { alpha = c0; beta = -s0; plane = Q0; }
  if (i == Q0) { alpha = c0; beta =  s0; plane = P0; }
  if (i == P1) { alpha = c1; beta = -s1; plane = Q1; }
  if (i == Q1) { alpha = c1; beta =  s1; plane = P1; }
  if (i == P2) { alpha = c2; beta = -s2; plane = Q2; }
  if (i == Q2) { alpha = c2; beta =  s2; plane = P2; }
  if (i == P3) { alpha = c3; beta = -s3; plane = Q3; }
  if (i == Q3) { alpha = c3; beta =  s3; plane = P3; }
  float prow[8];
#pragma unroll
  for (int j = 0; j < 8; ++j) prow[j] = __shfl(r[j], plane, 64);
#pragma unroll
  for (int j = 0; j < 8; ++j) r[j] = alpha * r[j] + beta * prow[j];
}

// ------- Kernel C: redundant per-block eigensolve (wave 0) + quad projection -------
__global__ __launch_bounds__(TPB, 4)
void project_solve_kernel(const float* __restrict__ x,
                          const double* __restrict__ sums_d,
                          float* __restrict__ out,
                          float* __restrict__ out_tail) {
  __shared__ double sums[NACC];
  __shared__ float s_res[9];
  int t = threadIdx.x;

  if (t < NACC) sums[t] = sums_d[t];
  __syncthreads();

  if (t < 64) {   // wave 0 solves; waves 1-3 wait at the barrier
    const int i = t & 7;
    const double invN = 1.0 / (double)NB;
    double mean[8];
#pragma unroll
    for (int j = 0; j < 8; ++j) mean[j] = sums[j] * invN;
    double mean_i = mean[0];
#pragma unroll
    for (int k = 1; k < 8; ++k) if (i == k) mean_i = mean[k];
    double rowd[8];
#pragma unroll
    for (int j = 0; j < 8; ++j) {
      int p = i < j ? i : j;
      int q = i < j ? j : i;
      int idx = 8 + p * 8 - (p * (p - 1)) / 2 + (q - p);
      rowd[j] = sums[idx] - (double)NB * mean_i * mean[j];
    }
    double tr = 0.0;
#pragma unroll
    for (int k = 0; k < 8; ++k) tr += __shfl(rowd[k], k, 64);
    double shift = tr * 0.125;

    float r[8], v[8];
#pragma unroll
    for (int j = 0; j < 8; ++j) {
      double d = rowd[j] - (j == i ? shift : 0.0);
      r[j] = (float)(d * (1.0 / 1536.0));
      v[j] = (j == i) ? 1.0f : 0.0f;
    }
#pragma unroll 1
    for (int sweep = 0; sweep < 6; ++sweep) {
      jacobi_round<7,0, 1,6, 2,5, 3,4>(r, v, i);
      jacobi_round<7,1, 2,0, 3,6, 4,5>(r, v, i);
      jacobi_round<7,2, 3,1, 4,0, 5,6>(r, v, i);
      jacobi_round<7,3, 4,2, 5,1, 6,0>(r, v, i);
      jacobi_round<7,4, 5,3, 6,2, 0,1>(r, v, i);
      jacobi_round<7,5, 6,4, 0,3, 1,2>(r, v, i);
      jacobi_round<7,6, 0,5, 1,4, 2,3>(r, v, i);
    }
    float diag[8];
#pragma unroll
    for (int k = 0; k < 8; ++k) diag[k] = rdlane(r[k], k);
    int best = 0; float bd = diag[0];
#pragma unroll
    for (int k = 1; k < 8; ++k) if (diag[k] > bd) { bd = diag[k]; best = k; }
    float vi = v[0];
#pragma unroll
    for (int k = 1; k < 8; ++k) if (best == k) vi = v[k];
    float vec[8];
#pragma unroll
    for (int k = 0; k < 8; ++k) vec[k] = rdlane(vi, k);
    float nrm2 = 0.0f;
#pragma unroll
    for (int k = 0; k < 8; ++k) nrm2 += vec[k] * vec[k];
    float inv = 1.0f / sqrtf(nrm2);
#pragma unroll
    for (int k = 0; k < 8; ++k) vec[k] *= inv;
    // sign convention (measured vs LAPACK round 1/2): largest-|component| NEGATIVE
    int m = 0; float am = fabsf(vec[0]);
#pragma unroll
    for (int k = 1; k < 8; ++k) { float aa = fabsf(vec[k]); if (aa > am) { am = aa; m = k; } }
    float vm = vec[0];
#pragma unroll
    for (int k = 1; k < 8; ++k) if (m == k) vm = vec[k];
    if (vm > 0.0f) {
#pragma unroll
      for (int k = 0; k < 8; ++k) vec[k] = -vec[k];
    }
    double c0d = 0.0;
#pragma unroll
    for (int k = 0; k < 8; ++k) c0d += mean[k] * (double)vec[k];
    float mi = (float)mean[0];
#pragma unroll
    for (int k = 1; k < 8; ++k) if (i == k) mi = (float)mean[k];
    float vl = vec[0];
#pragma unroll
    for (int k = 1; k < 8; ++k) if (i == k) vl = vec[k];

    if (t < 8) {
      s_res[t] = vl;
      if (blockIdx.x == 0) {
        out_tail[t]     = mi;   // mean
        out_tail[8 + t] = vl;   // pca_components
      }
    }
    if (t == 0) s_res[8] = (float)c0d;
  }
  __syncthreads();

  // quad projection: 8x float4 loads -> 4 outputs, float4 store (clean WRITE_SIZE)
  float w0 = s_res[0], w1 = s_res[1], w2 = s_res[2], w3 = s_res[3];
  float w4 = s_res[4], w5 = s_res[5], w6 = s_res[6], w7 = s_res[7];
  float c0 = s_res[8];
  float4* out4 = (float4*)out;
  const int stride = GRID_P * TPB;
  for (int q = blockIdx.x * TPB + t; q < NQUAD; q += stride) {  // exactly 3 iters
    int hq = q % 24;
    int t1 = q / 24;
    int wo = t1 % 96;
    int t2 = t1 / 96;
    int so = t2 % 32;
    int b  = t2 / 32;
    const float* base = x + (((b * 64 + 2 * so) * 192 + 2 * wo) * 192 + 8 * hq);
    float4 a0 = *(const float4*)(base);
    float4 b0 = *(const float4*)(base + 4);
    float4 a1 = *(const float4*)(base + 192);
    float4 b1 = *(const float4*)(base + 196);
    float4 a2 = *(const float4*)(base + 192 * 192);
    float4 b2 = *(const float4*)(base + 192 * 192 + 4);
    float4 a3 = *(const float4*)(base + 192 * 192 + 192);
    float4 b3 = *(const float4*)(base + 192 * 192 + 196);
    float o0 = a0.x * w0 + a0.y * w1 + a1.x * w2 + a1.y * w3
             + a2.x * w4 + a2.y * w5 + a3.x * w6 + a3.y * w7 - c0;
    float o1 = a0.z * w0 + a0.w * w1 + a1.z * w2 + a1.w * w3
             + a2.z * w4 + a2.w * w5 + a3.z * w6 + a3.w * w7 - c0;
    float o2 = b0.x * w0 + b0.y * w1 + b1.x * w2 + b1.y * w3
             + b2.x * w4 + b2.y * w5 + b3.x * w6 + b3.y * w7 - c0;
    float o3 = b0.z * w0 + b0.w * w1 + b1.z * w2 + b1.w * w3
             + b2.z * w4 + b2.w * w5 + b3.z * w6 + b3.w * w7 - c0;
    out4[q] = make_float4(o0, o1, o2, o3);
  }
}

extern "C" void kernel_launch(void* const* d_in, const int* in_sizes, int n_in,
                              void* d_out, int out_size, void* d_ws, size_t ws_size,
                              hipStream_t stream) {
  (void)in_sizes; (void)n_in; (void)out_size; (void)ws_size;
  const float* x = (const float*)d_in[0];
  float* out = (float*)d_out;
  float* partials = (float*)d_ws;                        // 44*768 f32 = 135 KB
  double* sums_d  = (double*)(partials + NACC * GRID_A); // 44 f64 (8B-aligned)

  reduce_kernel<<<GRID_A, TPB, 0, stream>>>(x, partials);
  mid_reduce_kernel<<<NACC, TPB, 0, stream>>>(partials, sums_d);
  project_solve_kernel<<<GRID_P, TPB, 0, stream>>>(x, sums_d, out, out + NB);
}